// Round 1
// baseline (3889.469 us; speedup 1.0000x reference)
//
#include <hip/hip_runtime.h>
#include <math.h>

#define DCH 64
#define TD 192      // 3*D
#define RR 20
#define FCUT 5.0f

// ---------------- Kernel A: per-atom MLP  h = silu(se@W1+b1)@W2+b2 ----------
__global__ __launch_bounds__(256) void mlp_kernel(
    const float* __restrict__ se,
    const float* __restrict__ W1, const float* __restrict__ b1,
    const float* __restrict__ W2, const float* __restrict__ b2,
    float* __restrict__ h, int N)
{
    const int wid  = threadIdx.x >> 6;
    const int lane = threadIdx.x & 63;
    const int waveGlobal = blockIdx.x * 4 + wid;
    const int stride = gridDim.x * 4;

    const float b1l = b1[lane];
    const float b20 = b2[lane], b21 = b2[DCH + lane], b22 = b2[2*DCH + lane];

    for (int a = waveGlobal; a < N; a += stride) {
        float sv = se[(size_t)a * DCH + lane];
        float acc = b1l;
        #pragma unroll
        for (int i = 0; i < DCH; ++i) {
            float si = __shfl(sv, i, 64);
            acc = fmaf(si, W1[i * DCH + lane], acc);
        }
        // SiLU
        float hid = acc / (1.0f + expf(-acc));
        float o0 = b20, o1 = b21, o2 = b22;
        #pragma unroll
        for (int j = 0; j < DCH; ++j) {
            float hj = __shfl(hid, j, 64);
            o0 = fmaf(hj, W2[j * TD + lane],          o0);
            o1 = fmaf(hj, W2[j * TD + DCH + lane],    o1);
            o2 = fmaf(hj, W2[j * TD + 2*DCH + lane],  o2);
        }
        size_t hb = (size_t)a * TD;
        h[hb + lane]           = o0;
        h[hb + DCH + lane]     = o1;
        h[hb + 2*DCH + lane]   = o2;
    }
}

// ---------------- Kernel B: per-edge filter + gather + scatter --------------
__global__ __launch_bounds__(256) void edge_kernel(
    const float* __restrict__ ve, const float* __restrict__ nv,
    const int*  __restrict__ central, const int* __restrict__ neigh,
    const float* __restrict__ freqs, const float* __restrict__ Wf,
    const float* __restrict__ bfil, const float* __restrict__ h,
    float* __restrict__ dv, float* __restrict__ ds, int E)
{
    const int wid  = threadIdx.x >> 6;
    const int lane = threadIdx.x & 63;

    // hoisted per-lane filter weights: W_filter[r, lane + t*64]
    float wf0[RR], wf1[RR], wf2[RR];
    #pragma unroll
    for (int r = 0; r < RR; ++r) {
        wf0[r] = Wf[r * TD + lane];
        wf1[r] = Wf[r * TD + DCH + lane];
        wf2[r] = Wf[r * TD + 2*DCH + lane];
    }
    const float bf0 = bfil[lane], bf1 = bfil[DCH + lane], bf2 = bfil[2*DCH + lane];
    const float myfreq = freqs[lane < RR ? lane : (RR - 1)];
    const float BC = sqrtf(2.0f / FCUT);

    const int waveGlobal = blockIdx.x * 4 + wid;
    const int stride = gridDim.x * 4;

    for (int e = waveGlobal; e < E; e += stride) {
        float x = nv[(size_t)e * 3 + 0];
        float y = nv[(size_t)e * 3 + 1];
        float z = nv[(size_t)e * 3 + 2];
        float dist = sqrtf(x * x + y * y + z * z);
        float inv  = 1.0f / dist;

        // lane r (<20) computes bessel_r; broadcast via shfl in the matvec
        float sv = BC * sinf(myfreq * dist) * inv;

        float acc0 = bf0, acc1 = bf1, acc2 = bf2;
        #pragma unroll
        for (int r = 0; r < RR; ++r) {
            float br = __shfl(sv, r, 64);
            acc0 = fmaf(br, wf0[r], acc0);
            acc1 = fmaf(br, wf1[r], acc1);
            acc2 = fmaf(br, wf2[r], acc2);
        }

        // polynomial envelope p=6
        float u  = dist * (1.0f / FCUT);
        float u2 = u * u;
        float u6 = u2 * u2 * u2;
        float env = 1.0f + u6 * (-28.0f + u * (48.0f - 21.0f * u));
        env = (dist < FCUT) ? env : 0.0f;
        acc0 *= env; acc1 *= env; acc2 *= env;

        int ca = central[e];
        int na = neigh[e];

        size_t hb = (size_t)ca * TD;
        float a_ = acc0 * h[hb + lane];
        float b_ = acc1 * h[hb + DCH + lane];
        float c_ = acc2 * h[hb + 2*DCH + lane];

        // delta_s scatter
        atomicAdd(ds + (size_t)na * DCH + lane, a_);

        // delta_v scatter: v = b*unit + c*ve[neigh]
        float ux = x * inv, uy = y * inv, uz = z * inv;
        size_t vb = (size_t)na * TD + lane * 3;
        float v0 = ve[vb + 0], v1 = ve[vb + 1], v2 = ve[vb + 2];
        atomicAdd(dv + vb + 0, fmaf(b_, ux, c_ * v0));
        atomicAdd(dv + vb + 1, fmaf(b_, uy, c_ * v1));
        atomicAdd(dv + vb + 2, fmaf(b_, uz, c_ * v2));
    }
}

extern "C" void kernel_launch(void* const* d_in, const int* in_sizes, int n_in,
                              void* d_out, int out_size, void* d_ws, size_t ws_size,
                              hipStream_t stream) {
    const float* ve      = (const float*)d_in[0];   // [N, 64, 3]
    const float* se      = (const float*)d_in[1];   // [N, 64]
    const float* nv      = (const float*)d_in[2];   // [E, 3]
    const int*   central = (const int*)  d_in[3];   // [E]
    const int*   neigh   = (const int*)  d_in[4];   // [E]
    const float* freqs   = (const float*)d_in[5];   // [20]
    const float* Wf      = (const float*)d_in[6];   // [20, 192]
    const float* bfil    = (const float*)d_in[7];   // [192]
    const float* W1      = (const float*)d_in[8];   // [64, 64]
    const float* b1      = (const float*)d_in[9];   // [64]
    const float* W2      = (const float*)d_in[10];  // [64, 192]
    const float* b2      = (const float*)d_in[11];  // [192]

    const int N = in_sizes[1] / DCH;
    const int E = in_sizes[3];

    float* out = (float*)d_out;
    float* dv  = out;                       // [N, 64, 3]
    float* ds  = out + (size_t)N * TD;      // [N, 64]
    float* h   = (float*)d_ws;              // [N, 192] scratch

    // outputs are accumulated with atomics -> zero them every call
    hipMemsetAsync(d_out, 0, (size_t)out_size * sizeof(float), stream);

    mlp_kernel<<<2048, 256, 0, stream>>>(se, W1, b1, W2, b2, h, N);
    edge_kernel<<<4096, 256, 0, stream>>>(ve, nv, central, neigh, freqs, Wf, bfil,
                                          h, dv, ds, E);
}

// Round 2
// 989.112 us; speedup vs baseline: 3.9323x; 3.9323x over previous
//
#include <hip/hip_runtime.h>
#include <math.h>

#define DCH 64
#define TD 192      // 3*D
#define RR 20
#define FCUT 5.0f

// ---------------- Kernel A: per-atom MLP, 4 atoms per wave-iter -------------
__global__ __launch_bounds__(256) void mlp_kernel(
    const float* __restrict__ se,
    const float* __restrict__ W1, const float* __restrict__ b1,
    const float* __restrict__ W2, const float* __restrict__ b2,
    float* __restrict__ h, int N)
{
    const int wid  = threadIdx.x >> 6;
    const int lane = threadIdx.x & 63;
    const int wave = blockIdx.x * 4 + wid;
    const int wstride = gridDim.x * 4;

    const float b1l = b1[lane];
    const float b20 = b2[lane], b21 = b2[DCH + lane], b22 = b2[2*DCH + lane];

    for (int base = wave * 4; base < N; base += wstride * 4) {
        float sv[4];
        #pragma unroll
        for (int k = 0; k < 4; ++k) {
            int a = base + k;
            sv[k] = (a < N) ? se[(size_t)a * DCH + lane] : 0.0f;
        }
        float acc[4] = {b1l, b1l, b1l, b1l};
        #pragma unroll
        for (int i = 0; i < DCH; ++i) {
            float w = W1[i * DCH + lane];
            #pragma unroll
            for (int k = 0; k < 4; ++k)
                acc[k] = fmaf(__shfl(sv[k], i, 64), w, acc[k]);
        }
        float hid[4];
        #pragma unroll
        for (int k = 0; k < 4; ++k)
            hid[k] = acc[k] / (1.0f + expf(-acc[k]));   // SiLU

        float o0[4] = {b20,b20,b20,b20};
        float o1[4] = {b21,b21,b21,b21};
        float o2[4] = {b22,b22,b22,b22};
        #pragma unroll
        for (int j = 0; j < DCH; ++j) {
            float w0 = W2[j * TD + lane];
            float w1 = W2[j * TD + DCH + lane];
            float w2 = W2[j * TD + 2*DCH + lane];
            #pragma unroll
            for (int k = 0; k < 4; ++k) {
                float hj = __shfl(hid[k], j, 64);
                o0[k] = fmaf(hj, w0, o0[k]);
                o1[k] = fmaf(hj, w1, o1[k]);
                o2[k] = fmaf(hj, w2, o2[k]);
            }
        }
        #pragma unroll
        for (int k = 0; k < 4; ++k) {
            int a = base + k;
            if (a < N) {
                size_t hb = (size_t)a * TD;
                h[hb + lane]         = o0[k];
                h[hb + DCH + lane]   = o1[k];
                h[hb + 2*DCH + lane] = o2[k];
            }
        }
    }
}

// ---------------- CSR build: histogram, scan, fill --------------------------
__global__ void hist_kernel(const int* __restrict__ neigh,
                            int* __restrict__ counts, int* __restrict__ pos, int E)
{
    int stride = gridDim.x * blockDim.x;
    for (int e = blockIdx.x * blockDim.x + threadIdx.x; e < E; e += stride)
        pos[e] = atomicAdd(&counts[neigh[e]], 1);
}

__global__ __launch_bounds__(256) void scan1_kernel(
    const int* __restrict__ counts, int* __restrict__ starts,
    int* __restrict__ bsums, int N)
{
    int tid = threadIdx.x;
    int gid = blockIdx.x * 256 + tid;
    int v = (gid < N) ? counts[gid] : 0;
    int lane = tid & 63, wid = tid >> 6;
    int x = v;
    #pragma unroll
    for (int off = 1; off < 64; off <<= 1) {
        int y = __shfl_up(x, off, 64);
        if (lane >= off) x += y;
    }
    __shared__ int wsum[4];
    if (lane == 63) wsum[wid] = x;
    __syncthreads();
    int add = 0;
    for (int w = 0; w < wid; ++w) add += wsum[w];
    int incl = x + add;
    if (gid < N) starts[gid] = incl - v;          // block-local exclusive
    if (tid == 255) bsums[blockIdx.x] = incl;     // block total
}

__global__ __launch_bounds__(512) void scan2_kernel(int* __restrict__ bsums, int M)
{
    int tid = threadIdx.x;
    int v = (tid < M) ? bsums[tid] : 0;
    int lane = tid & 63, wid = tid >> 6;
    int x = v;
    #pragma unroll
    for (int off = 1; off < 64; off <<= 1) {
        int y = __shfl_up(x, off, 64);
        if (lane >= off) x += y;
    }
    __shared__ int wsum[8];
    if (lane == 63) wsum[wid] = x;
    __syncthreads();
    int add = 0;
    for (int w = 0; w < wid; ++w) add += wsum[w];
    int incl = x + add;
    if (tid < M) bsums[tid] = incl - v;           // exclusive scan in place
}

__global__ __launch_bounds__(256) void scan3_kernel(
    int* __restrict__ starts, const int* __restrict__ bsums, int N)
{
    int gid = blockIdx.x * 256 + threadIdx.x;
    if (gid < N) starts[gid] += bsums[blockIdx.x];
}

__global__ void fill_kernel(const float* __restrict__ nv, const int* __restrict__ central,
                            const int* __restrict__ neigh, const int* __restrict__ starts,
                            const int* __restrict__ pos, float4* __restrict__ payload, int E)
{
    int stride = gridDim.x * blockDim.x;
    for (int e = blockIdx.x * blockDim.x + threadIdx.x; e < E; e += stride) {
        int slot = starts[neigh[e]] + pos[e];
        payload[slot] = make_float4(nv[(size_t)e*3+0], nv[(size_t)e*3+1],
                                    nv[(size_t)e*3+2], __int_as_float(central[e]));
    }
}

// ---------------- Kernel C: per-atom gather, no atomics ---------------------
__global__ __launch_bounds__(256) void gather_kernel(
    const float4* __restrict__ payload, const int* __restrict__ starts,
    const int* __restrict__ counts, const float* __restrict__ h,
    const float* __restrict__ ve, const float* __restrict__ freqs,
    const float* __restrict__ Wf, const float* __restrict__ bfil,
    float* __restrict__ dv, float* __restrict__ ds, int N)
{
    const int wid  = threadIdx.x >> 6;
    const int lane = threadIdx.x & 63;
    const int atom = blockIdx.x * 4 + wid;
    if (atom >= N) return;

    float wf0[RR], wf1[RR], wf2[RR];
    #pragma unroll
    for (int r = 0; r < RR; ++r) {
        wf0[r] = Wf[r * TD + lane];
        wf1[r] = Wf[r * TD + DCH + lane];
        wf2[r] = Wf[r * TD + 2*DCH + lane];
    }
    const float bf0 = bfil[lane], bf1 = bfil[DCH + lane], bf2 = bfil[2*DCH + lane];
    const float myfreq = freqs[lane < RR ? lane : (RR - 1)];
    const float BC = sqrtf(2.0f / FCUT);

    const int s   = starts[atom];
    const int cnt = counts[atom];

    float ds_acc = 0.0f, dvx = 0.0f, dvy = 0.0f, dvz = 0.0f, csum = 0.0f;

    auto body = [&](float4 p) {
        int ca = __float_as_int(p.w);
        size_t hb = (size_t)ca * TD;
        float h0 = h[hb + lane];
        float h1 = h[hb + DCH + lane];
        float h2 = h[hb + 2*DCH + lane];

        float dist = sqrtf(p.x*p.x + p.y*p.y + p.z*p.z);
        float inv  = 1.0f / dist;
        float svb  = BC * sinf(myfreq * dist) * inv;   // lane r < 20 valid

        float acc0 = bf0, acc1 = bf1, acc2 = bf2;
        #pragma unroll
        for (int r = 0; r < RR; ++r) {
            float br = __shfl(svb, r, 64);
            acc0 = fmaf(br, wf0[r], acc0);
            acc1 = fmaf(br, wf1[r], acc1);
            acc2 = fmaf(br, wf2[r], acc2);
        }
        float u  = dist * (1.0f / FCUT);
        float u2 = u * u;
        float u6 = u2 * u2 * u2;
        float env = 1.0f + u6 * (-28.0f + u * (48.0f - 21.0f * u));
        env = (dist < FCUT) ? env : 0.0f;

        float a_ = acc0 * env * h0;
        float b_ = acc1 * env * h1;
        float c_ = acc2 * env * h2;

        ds_acc += a_;
        dvx = fmaf(b_, p.x * inv, dvx);
        dvy = fmaf(b_, p.y * inv, dvy);
        dvz = fmaf(b_, p.z * inv, dvz);
        csum += c_;
    };

    int i = 0;
    for (; i + 1 < cnt; i += 2) {      // 2-edge interleave for ILP
        float4 p0 = payload[s + i];
        float4 p1 = payload[s + i + 1];
        body(p0);
        body(p1);
    }
    if (i < cnt) body(payload[s + i]);

    // single write per output element; (sum c) * ve[atom] folded in here
    size_t vb = (size_t)atom * TD + (size_t)lane * 3;
    float v0 = ve[vb + 0], v1 = ve[vb + 1], v2 = ve[vb + 2];
    dv[vb + 0] = fmaf(csum, v0, dvx);
    dv[vb + 1] = fmaf(csum, v1, dvy);
    dv[vb + 2] = fmaf(csum, v2, dvz);
    ds[(size_t)atom * DCH + lane] = ds_acc;
}

// ---------------- fallback: round-1 atomic edge kernel ----------------------
__global__ __launch_bounds__(256) void edge_kernel(
    const float* __restrict__ ve, const float* __restrict__ nv,
    const int*  __restrict__ central, const int* __restrict__ neigh,
    const float* __restrict__ freqs, const float* __restrict__ Wf,
    const float* __restrict__ bfil, const float* __restrict__ h,
    float* __restrict__ dv, float* __restrict__ ds, int E)
{
    const int wid  = threadIdx.x >> 6;
    const int lane = threadIdx.x & 63;
    float wf0[RR], wf1[RR], wf2[RR];
    #pragma unroll
    for (int r = 0; r < RR; ++r) {
        wf0[r] = Wf[r * TD + lane];
        wf1[r] = Wf[r * TD + DCH + lane];
        wf2[r] = Wf[r * TD + 2*DCH + lane];
    }
    const float bf0 = bfil[lane], bf1 = bfil[DCH + lane], bf2 = bfil[2*DCH + lane];
    const float myfreq = freqs[lane < RR ? lane : (RR - 1)];
    const float BC = sqrtf(2.0f / FCUT);
    const int waveGlobal = blockIdx.x * 4 + wid;
    const int stride = gridDim.x * 4;
    for (int e = waveGlobal; e < E; e += stride) {
        float x = nv[(size_t)e*3+0], y = nv[(size_t)e*3+1], z = nv[(size_t)e*3+2];
        float dist = sqrtf(x*x + y*y + z*z);
        float inv  = 1.0f / dist;
        float sv = BC * sinf(myfreq * dist) * inv;
        float acc0 = bf0, acc1 = bf1, acc2 = bf2;
        #pragma unroll
        for (int r = 0; r < RR; ++r) {
            float br = __shfl(sv, r, 64);
            acc0 = fmaf(br, wf0[r], acc0);
            acc1 = fmaf(br, wf1[r], acc1);
            acc2 = fmaf(br, wf2[r], acc2);
        }
        float u = dist * (1.0f/FCUT), u2 = u*u, u6 = u2*u2*u2;
        float env = 1.0f + u6 * (-28.0f + u * (48.0f - 21.0f * u));
        env = (dist < FCUT) ? env : 0.0f;
        acc0 *= env; acc1 *= env; acc2 *= env;
        int ca = central[e], na = neigh[e];
        size_t hb = (size_t)ca * TD;
        float a_ = acc0 * h[hb + lane];
        float b_ = acc1 * h[hb + DCH + lane];
        float c_ = acc2 * h[hb + 2*DCH + lane];
        atomicAdd(ds + (size_t)na * DCH + lane, a_);
        float ux = x*inv, uy = y*inv, uz = z*inv;
        size_t vb = (size_t)na * TD + lane*3;
        float v0 = ve[vb+0], v1 = ve[vb+1], v2 = ve[vb+2];
        atomicAdd(dv + vb + 0, fmaf(b_, ux, c_ * v0));
        atomicAdd(dv + vb + 1, fmaf(b_, uy, c_ * v1));
        atomicAdd(dv + vb + 2, fmaf(b_, uz, c_ * v2));
    }
}

extern "C" void kernel_launch(void* const* d_in, const int* in_sizes, int n_in,
                              void* d_out, int out_size, void* d_ws, size_t ws_size,
                              hipStream_t stream) {
    const float* ve      = (const float*)d_in[0];
    const float* se      = (const float*)d_in[1];
    const float* nv      = (const float*)d_in[2];
    const int*   central = (const int*)  d_in[3];
    const int*   neigh   = (const int*)  d_in[4];
    const float* freqs   = (const float*)d_in[5];
    const float* Wf      = (const float*)d_in[6];
    const float* bfil    = (const float*)d_in[7];
    const float* W1      = (const float*)d_in[8];
    const float* b1      = (const float*)d_in[9];
    const float* W2      = (const float*)d_in[10];
    const float* b2      = (const float*)d_in[11];

    const int N = in_sizes[1] / DCH;
    const int E = in_sizes[3];

    float* out = (float*)d_out;
    float* dv  = out;
    float* ds  = out + (size_t)N * TD;

    // ws layout (256B aligned)
    char* wsb = (char*)d_ws;
    size_t off = 0;
    auto wsalloc = [&](size_t bytes) -> void* {
        void* p = wsb + off;
        off = (off + bytes + 255) & ~(size_t)255;
        return p;
    };
    float*  h       = (float*) wsalloc((size_t)N * TD * 4);
    int*    counts  = (int*)   wsalloc((size_t)N * 4);
    int*    starts  = (int*)   wsalloc((size_t)N * 4);
    int*    pos     = (int*)   wsalloc((size_t)E * 4);
    float4* payload = (float4*)wsalloc((size_t)E * 16);
    int*    bsums   = (int*)   wsalloc(4096);

    const int nb1 = (N + 255) / 256;
    const bool csr_ok = (off <= ws_size) && (nb1 <= 512);

    mlp_kernel<<<2048, 256, 0, stream>>>(se, W1, b1, W2, b2, h, N);

    if (csr_ok) {
        hipMemsetAsync(counts, 0, (size_t)N * 4, stream);
        hist_kernel<<<2048, 256, 0, stream>>>(neigh, counts, pos, E);
        scan1_kernel<<<nb1, 256, 0, stream>>>(counts, starts, bsums, N);
        scan2_kernel<<<1, 512, 0, stream>>>(bsums, nb1);
        scan3_kernel<<<nb1, 256, 0, stream>>>(starts, bsums, N);
        fill_kernel<<<2048, 256, 0, stream>>>(nv, central, neigh, starts, pos, payload, E);
        gather_kernel<<<(N + 3) / 4, 256, 0, stream>>>(payload, starts, counts, h, ve,
                                                       freqs, Wf, bfil, dv, ds, N);
    } else {
        hipMemsetAsync(d_out, 0, (size_t)out_size * sizeof(float), stream);
        edge_kernel<<<4096, 256, 0, stream>>>(ve, nv, central, neigh, freqs, Wf, bfil,
                                              h, dv, ds, E);
    }
}

// Round 3
// 863.557 us; speedup vs baseline: 4.5040x; 1.1454x over previous
//
#include <hip/hip_runtime.h>
#include <math.h>

#define DCH 64
#define TD 192      // 3*D
#define RR 20
#define FCUT 5.0f

// ---------------- Kernel A: per-atom MLP, 4 atoms per wave-iter -------------
__global__ __launch_bounds__(256) void mlp_kernel(
    const float* __restrict__ se,
    const float* __restrict__ W1, const float* __restrict__ b1,
    const float* __restrict__ W2, const float* __restrict__ b2,
    float* __restrict__ h, int N)
{
    const int wid  = threadIdx.x >> 6;
    const int lane = threadIdx.x & 63;
    const int wave = blockIdx.x * 4 + wid;
    const int wstride = gridDim.x * 4;

    const float b1l = b1[lane];
    const float b20 = b2[lane], b21 = b2[DCH + lane], b22 = b2[2*DCH + lane];

    for (int base = wave * 4; base < N; base += wstride * 4) {
        float sv[4];
        #pragma unroll
        for (int k = 0; k < 4; ++k) {
            int a = base + k;
            sv[k] = (a < N) ? se[(size_t)a * DCH + lane] : 0.0f;
        }
        float acc[4] = {b1l, b1l, b1l, b1l};
        #pragma unroll
        for (int i = 0; i < DCH; ++i) {
            float w = W1[i * DCH + lane];
            #pragma unroll
            for (int k = 0; k < 4; ++k)
                acc[k] = fmaf(__shfl(sv[k], i, 64), w, acc[k]);
        }
        float hid[4];
        #pragma unroll
        for (int k = 0; k < 4; ++k)
            hid[k] = acc[k] / (1.0f + expf(-acc[k]));   // SiLU

        float o0[4] = {b20,b20,b20,b20};
        float o1[4] = {b21,b21,b21,b21};
        float o2[4] = {b22,b22,b22,b22};
        #pragma unroll
        for (int j = 0; j < DCH; ++j) {
            float w0 = W2[j * TD + lane];
            float w1 = W2[j * TD + DCH + lane];
            float w2 = W2[j * TD + 2*DCH + lane];
            #pragma unroll
            for (int k = 0; k < 4; ++k) {
                float hj = __shfl(hid[k], j, 64);
                o0[k] = fmaf(hj, w0, o0[k]);
                o1[k] = fmaf(hj, w1, o1[k]);
                o2[k] = fmaf(hj, w2, o2[k]);
            }
        }
        #pragma unroll
        for (int k = 0; k < 4; ++k) {
            int a = base + k;
            if (a < N) {
                size_t hb = (size_t)a * TD;
                h[hb + lane]         = o0[k];
                h[hb + DCH + lane]   = o1[k];
                h[hb + 2*DCH + lane] = o2[k];
            }
        }
    }
}

// ---------------- CSR build: histogram, scan, fill --------------------------
__global__ void hist_kernel(const int* __restrict__ neigh,
                            int* __restrict__ counts, int* __restrict__ pos, int E)
{
    int stride = gridDim.x * blockDim.x;
    for (int e = blockIdx.x * blockDim.x + threadIdx.x; e < E; e += stride)
        pos[e] = atomicAdd(&counts[neigh[e]], 1);
}

__global__ __launch_bounds__(256) void scan1_kernel(
    const int* __restrict__ counts, int* __restrict__ starts,
    int* __restrict__ bsums, int N)
{
    int tid = threadIdx.x;
    int gid = blockIdx.x * 256 + tid;
    int v = (gid < N) ? counts[gid] : 0;
    int lane = tid & 63, wid = tid >> 6;
    int x = v;
    #pragma unroll
    for (int off = 1; off < 64; off <<= 1) {
        int y = __shfl_up(x, off, 64);
        if (lane >= off) x += y;
    }
    __shared__ int wsum[4];
    if (lane == 63) wsum[wid] = x;
    __syncthreads();
    int add = 0;
    for (int w = 0; w < wid; ++w) add += wsum[w];
    int incl = x + add;
    if (gid < N) starts[gid] = incl - v;          // block-local exclusive
    if (tid == 255) bsums[blockIdx.x] = incl;     // block total
}

__global__ __launch_bounds__(512) void scan2_kernel(int* __restrict__ bsums, int M)
{
    int tid = threadIdx.x;
    int v = (tid < M) ? bsums[tid] : 0;
    int lane = tid & 63, wid = tid >> 6;
    int x = v;
    #pragma unroll
    for (int off = 1; off < 64; off <<= 1) {
        int y = __shfl_up(x, off, 64);
        if (lane >= off) x += y;
    }
    __shared__ int wsum[8];
    if (lane == 63) wsum[wid] = x;
    __syncthreads();
    int add = 0;
    for (int w = 0; w < wid; ++w) add += wsum[w];
    int incl = x + add;
    if (tid < M) bsums[tid] = incl - v;           // exclusive scan in place
}

__global__ __launch_bounds__(256) void scan3_kernel(
    int* __restrict__ starts, const int* __restrict__ bsums, int N)
{
    int gid = blockIdx.x * 256 + threadIdx.x;
    if (gid < N) starts[gid] += bsums[blockIdx.x];
}

__global__ void fill_kernel(const float* __restrict__ nv, const int* __restrict__ central,
                            const int* __restrict__ neigh, const int* __restrict__ starts,
                            const int* __restrict__ pos, float4* __restrict__ payload, int E)
{
    int stride = gridDim.x * blockDim.x;
    for (int e = blockIdx.x * blockDim.x + threadIdx.x; e < E; e += stride) {
        int slot = starts[neigh[e]] + pos[e];
        payload[slot] = make_float4(nv[(size_t)e*3+0], nv[(size_t)e*3+1],
                                    nv[(size_t)e*3+2], __int_as_float(central[e]));
    }
}

// ---------------- Kernel C: per-atom gather, no atomics, no shfl ------------
// Bessel basis via Chebyshev recurrence: sin((n+1)x) = 2cos(x)sin(nx) - sin((n-1)x)
__global__ __launch_bounds__(256) void gather_kernel(
    const float4* __restrict__ payload, const int* __restrict__ starts,
    const int* __restrict__ counts, const float* __restrict__ h,
    const float* __restrict__ ve, const float* __restrict__ Wf,
    const float* __restrict__ bfil,
    float* __restrict__ dv, float* __restrict__ ds, int N)
{
    const int wid  = threadIdx.x >> 6;
    const int lane = threadIdx.x & 63;
    const int atom = blockIdx.x * 4 + wid;
    if (atom >= N) return;

    // hoisted per-lane filter weights: W_filter[r, lane + t*64]
    float wf0[RR], wf1[RR], wf2[RR];
    #pragma unroll
    for (int r = 0; r < RR; ++r) {
        wf0[r] = Wf[r * TD + lane];
        wf1[r] = Wf[r * TD + DCH + lane];
        wf2[r] = Wf[r * TD + 2*DCH + lane];
    }
    const float bf0 = bfil[lane], bf1 = bfil[DCH + lane], bf2 = bfil[2*DCH + lane];
    const float BC = sqrtf(2.0f / FCUT);
    const float XK = (float)(M_PI / (double)FCUT);   // x = d * pi/cutoff

    const int s   = starts[atom];
    const int cnt = counts[atom];

    float ds_acc = 0.0f, dvx = 0.0f, dvy = 0.0f, dvz = 0.0f, csum = 0.0f;

    auto body = [&](float4 p) {
        int ca = __float_as_int(p.w);
        size_t hb = (size_t)ca * TD;
        float h0 = h[hb + lane];
        float h1 = h[hb + DCH + lane];
        float h2 = h[hb + 2*DCH + lane];

        float dist = sqrtf(p.x*p.x + p.y*p.y + p.z*p.z);
        float inv  = 1.0f / dist;
        float x    = dist * XK;              // in (0, pi)
        float s1   = __sinf(x);
        float c1   = __cosf(x);
        float twoc = c1 + c1;

        // matvec with in-register recurrence (every lane has all basis vals)
        float acc0 = 0.0f, acc1 = 0.0f, acc2 = 0.0f;
        float sm1 = 0.0f, sn = s1;
        #pragma unroll
        for (int r = 0; r < RR; ++r) {
            acc0 = fmaf(sn, wf0[r], acc0);
            acc1 = fmaf(sn, wf1[r], acc1);
            acc2 = fmaf(sn, wf2[r], acc2);
            float nxt = fmaf(twoc, sn, -sm1);
            sm1 = sn; sn = nxt;
        }

        // envelope p=6
        float u  = dist * (1.0f / FCUT);
        float u2 = u * u;
        float u6 = u2 * u2 * u2;
        float env = 1.0f + u6 * (-28.0f + u * (48.0f - 21.0f * u));
        env = (dist < FCUT) ? env : 0.0f;

        // filt = (acc * BC/d + bf) * env
        float scale = BC * inv * env;
        float a_ = fmaf(acc0, scale, bf0 * env) * h0;
        float b_ = fmaf(acc1, scale, bf1 * env) * h1;
        float c_ = fmaf(acc2, scale, bf2 * env) * h2;

        ds_acc += a_;
        dvx = fmaf(b_, p.x * inv, dvx);
        dvy = fmaf(b_, p.y * inv, dvy);
        dvz = fmaf(b_, p.z * inv, dvz);
        csum += c_;
    };

    int i = 0;
    for (; i + 1 < cnt; i += 2) {      // 2-edge interleave for ILP
        float4 p0 = payload[s + i];
        float4 p1 = payload[s + i + 1];
        body(p0);
        body(p1);
    }
    if (i < cnt) body(payload[s + i]);

    // single write per output element; (sum c) * ve[atom] folded in here
    size_t vb = (size_t)atom * TD + (size_t)lane * 3;
    float v0 = ve[vb + 0], v1 = ve[vb + 1], v2 = ve[vb + 2];
    dv[vb + 0] = fmaf(csum, v0, dvx);
    dv[vb + 1] = fmaf(csum, v1, dvy);
    dv[vb + 2] = fmaf(csum, v2, dvz);
    ds[(size_t)atom * DCH + lane] = ds_acc;
}

extern "C" void kernel_launch(void* const* d_in, const int* in_sizes, int n_in,
                              void* d_out, int out_size, void* d_ws, size_t ws_size,
                              hipStream_t stream) {
    const float* ve      = (const float*)d_in[0];
    const float* se      = (const float*)d_in[1];
    const float* nv      = (const float*)d_in[2];
    const int*   central = (const int*)  d_in[3];
    const int*   neigh   = (const int*)  d_in[4];
    const float* Wf      = (const float*)d_in[6];
    const float* bfil    = (const float*)d_in[7];
    const float* W1      = (const float*)d_in[8];
    const float* b1      = (const float*)d_in[9];
    const float* W2      = (const float*)d_in[10];
    const float* b2      = (const float*)d_in[11];

    const int N = in_sizes[1] / DCH;
    const int E = in_sizes[3];

    float* out = (float*)d_out;
    float* dv  = out;
    float* ds  = out + (size_t)N * TD;

    // ws layout (256B aligned)
    char* wsb = (char*)d_ws;
    size_t off = 0;
    auto wsalloc = [&](size_t bytes) -> void* {
        void* p = wsb + off;
        off = (off + bytes + 255) & ~(size_t)255;
        return p;
    };
    float*  h       = (float*) wsalloc((size_t)N * TD * 4);
    int*    counts  = (int*)   wsalloc((size_t)N * 4);
    int*    starts  = (int*)   wsalloc((size_t)N * 4);
    int*    pos     = (int*)   wsalloc((size_t)E * 4);
    float4* payload = (float4*)wsalloc((size_t)E * 16);
    int*    bsums   = (int*)   wsalloc(4096);

    const int nb1 = (N + 255) / 256;

    mlp_kernel<<<2048, 256, 0, stream>>>(se, W1, b1, W2, b2, h, N);

    hipMemsetAsync(counts, 0, (size_t)N * 4, stream);
    hist_kernel<<<2048, 256, 0, stream>>>(neigh, counts, pos, E);
    scan1_kernel<<<nb1, 256, 0, stream>>>(counts, starts, bsums, N);
    scan2_kernel<<<1, 512, 0, stream>>>(bsums, nb1);
    scan3_kernel<<<nb1, 256, 0, stream>>>(starts, bsums, N);
    fill_kernel<<<2048, 256, 0, stream>>>(nv, central, neigh, starts, pos, payload, E);
    gather_kernel<<<(N + 3) / 4, 256, 0, stream>>>(payload, starts, counts, h, ve,
                                                   Wf, bfil, dv, ds, N);
}

// Round 4
// 710.100 us; speedup vs baseline: 5.4774x; 1.2161x over previous
//
#include <hip/hip_runtime.h>
#include <math.h>

#define DCH 64
#define TD 192      // 3*D
#define RR 20
#define FCUT 5.0f

typedef __attribute__((ext_vector_type(8))) short short8;   // 8 bf16
typedef __attribute__((ext_vector_type(4))) float f32x4;

__device__ __forceinline__ unsigned short f2bf(float f) {   // f32 -> bf16 RNE
    unsigned int u = __float_as_uint(f);
    u += 0x7FFFu + ((u >> 16) & 1u);
    return (unsigned short)(u >> 16);
}

// ---------------- Kernel A: per-atom MLP, 4 atoms per wave-iter -------------
__global__ __launch_bounds__(256) void mlp_kernel(
    const float* __restrict__ se,
    const float* __restrict__ W1, const float* __restrict__ b1,
    const float* __restrict__ W2, const float* __restrict__ b2,
    float* __restrict__ h, int N)
{
    const int wid  = threadIdx.x >> 6;
    const int lane = threadIdx.x & 63;
    const int wave = blockIdx.x * 4 + wid;
    const int wstride = gridDim.x * 4;

    const float b1l = b1[lane];
    const float b20 = b2[lane], b21 = b2[DCH + lane], b22 = b2[2*DCH + lane];

    for (int base = wave * 4; base < N; base += wstride * 4) {
        float sv[4];
        #pragma unroll
        for (int k = 0; k < 4; ++k) {
            int a = base + k;
            sv[k] = (a < N) ? se[(size_t)a * DCH + lane] : 0.0f;
        }
        float acc[4] = {b1l, b1l, b1l, b1l};
        #pragma unroll
        for (int i = 0; i < DCH; ++i) {
            float w = W1[i * DCH + lane];
            #pragma unroll
            for (int k = 0; k < 4; ++k)
                acc[k] = fmaf(__shfl(sv[k], i, 64), w, acc[k]);
        }
        float hid[4];
        #pragma unroll
        for (int k = 0; k < 4; ++k)
            hid[k] = acc[k] / (1.0f + expf(-acc[k]));   // SiLU

        float o0[4] = {b20,b20,b20,b20};
        float o1[4] = {b21,b21,b21,b21};
        float o2[4] = {b22,b22,b22,b22};
        #pragma unroll
        for (int j = 0; j < DCH; ++j) {
            float w0 = W2[j * TD + lane];
            float w1 = W2[j * TD + DCH + lane];
            float w2 = W2[j * TD + 2*DCH + lane];
            #pragma unroll
            for (int k = 0; k < 4; ++k) {
                float hj = __shfl(hid[k], j, 64);
                o0[k] = fmaf(hj, w0, o0[k]);
                o1[k] = fmaf(hj, w1, o1[k]);
                o2[k] = fmaf(hj, w2, o2[k]);
            }
        }
        #pragma unroll
        for (int k = 0; k < 4; ++k) {
            int a = base + k;
            if (a < N) {
                size_t hb = (size_t)a * TD;
                h[hb + lane]         = o0[k];
                h[hb + DCH + lane]   = o1[k];
                h[hb + 2*DCH + lane] = o2[k];
            }
        }
    }
}

// ---------------- CSR build: histogram, scan, fill --------------------------
__global__ void hist_kernel(const int* __restrict__ neigh,
                            int* __restrict__ counts, int* __restrict__ pos, int E)
{
    int stride = gridDim.x * blockDim.x;
    for (int e = blockIdx.x * blockDim.x + threadIdx.x; e < E; e += stride)
        pos[e] = atomicAdd(&counts[neigh[e]], 1);
}

__global__ __launch_bounds__(256) void scan1_kernel(
    const int* __restrict__ counts, int* __restrict__ starts,
    int* __restrict__ bsums, int N)
{
    int tid = threadIdx.x;
    int gid = blockIdx.x * 256 + tid;
    int v = (gid < N) ? counts[gid] : 0;
    int lane = tid & 63, wid = tid >> 6;
    int x = v;
    #pragma unroll
    for (int off = 1; off < 64; off <<= 1) {
        int y = __shfl_up(x, off, 64);
        if (lane >= off) x += y;
    }
    __shared__ int wsum[4];
    if (lane == 63) wsum[wid] = x;
    __syncthreads();
    int add = 0;
    for (int w = 0; w < wid; ++w) add += wsum[w];
    int incl = x + add;
    if (gid < N) starts[gid] = incl - v;          // block-local exclusive
    if (tid == 255) bsums[blockIdx.x] = incl;     // block total
}

__global__ __launch_bounds__(512) void scan2_kernel(int* __restrict__ bsums, int M)
{
    int tid = threadIdx.x;
    int v = (tid < M) ? bsums[tid] : 0;
    int lane = tid & 63, wid = tid >> 6;
    int x = v;
    #pragma unroll
    for (int off = 1; off < 64; off <<= 1) {
        int y = __shfl_up(x, off, 64);
        if (lane >= off) x += y;
    }
    __shared__ int wsum[8];
    if (lane == 63) wsum[wid] = x;
    __syncthreads();
    int add = 0;
    for (int w = 0; w < wid; ++w) add += wsum[w];
    int incl = x + add;
    if (tid < M) bsums[tid] = incl - v;           // exclusive scan in place
}

__global__ __launch_bounds__(256) void scan3_kernel(
    int* __restrict__ starts, const int* __restrict__ bsums, int N)
{
    int gid = blockIdx.x * 256 + threadIdx.x;
    if (gid < N) starts[gid] += bsums[blockIdx.x];
}

__global__ void fill_kernel(const float* __restrict__ nv, const int* __restrict__ central,
                            const int* __restrict__ neigh, const int* __restrict__ starts,
                            const int* __restrict__ pos, float4* __restrict__ payload, int E)
{
    int stride = gridDim.x * blockDim.x;
    for (int e = blockIdx.x * blockDim.x + threadIdx.x; e < E; e += stride) {
        int slot = starts[neigh[e]] + pos[e];
        payload[slot] = make_float4(nv[(size_t)e*3+0], nv[(size_t)e*3+1],
                                    nv[(size_t)e*3+2], __int_as_float(central[e]));
    }
}

// ---------------- Kernel C: per-atom gather, MFMA filter --------------------
// Per 16-edge batch: A[16e x 32k] = sin((k+1)*pi*d/5)*BC*env/d (bf16),
// B[32k x 16ch] = Wf tile (zero-padded k>=20). C = A@B per 12 channel tiles.
__global__ __launch_bounds__(256) void gather_kernel(
    const float4* __restrict__ payload, const int* __restrict__ starts,
    const int* __restrict__ counts, const float* __restrict__ h,
    const float* __restrict__ ve, const float* __restrict__ Wf,
    const float* __restrict__ bfil,
    float* __restrict__ dv, float* __restrict__ ds, int N)
{
    const int wid  = threadIdx.x >> 6;
    const int lane = threadIdx.x & 63;
    const int g    = lane >> 4;     // k-group (A/B), row-group (C)
    const int c    = lane & 15;     // own edge row (A), channel-in-tile (B/C)

    // hoisted B fragments + bias (constant per kernel)
    short8 Bf[12];
    float  bft[12];
    #pragma unroll
    for (int t = 0; t < 12; ++t) {
        #pragma unroll
        for (int j = 0; j < 8; ++j) {
            int r = 8 * g + j;
            float w = (r < RR) ? Wf[r * TD + 16 * t + c] : 0.0f;
            Bf[t][j] = (short)f2bf(w);
        }
        bft[t] = bfil[16 * t + c];
    }

    const float BC = sqrtf(2.0f / FCUT);
    const float XK = (float)(M_PI / (double)FCUT);
    const char* hb = (const char*)h;

    for (int atom = blockIdx.x * 4 + wid; atom < N; atom += gridDim.x * 4) {
        const int s   = starts[atom];
        const int cnt = counts[atom];

        float dsa[4] = {0,0,0,0};
        float csm[4] = {0,0,0,0};
        float dvx[4] = {0,0,0,0};
        float dvy[4] = {0,0,0,0};
        float dvz[4] = {0,0,0,0};

        for (int i0 = 0; i0 < cnt; i0 += 16) {
            // ---- lane owns edge m = c of this batch ----
            const bool valid = (i0 + c) < cnt;
            float4 p = valid ? payload[s + i0 + c]
                             : make_float4(1.0f, 0.0f, 0.0f, __int_as_float(0));
            float dist = sqrtf(p.x*p.x + p.y*p.y + p.z*p.z);
            float inv  = 1.0f / dist;
            float xa   = dist * XK;

            float u  = dist * (1.0f / FCUT);
            float u2 = u * u;
            float u6 = u2 * u2 * u2;
            float env = 1.0f + u6 * (-28.0f + u * (48.0f - 21.0f * u));
            env = (dist < FCUT && valid) ? env : 0.0f;
            float scale = BC * inv * env;

            float ux = p.x * inv, uy = p.y * inv, uz = p.z * inv;
            int   hof = __float_as_int(p.w) * (TD * 4);   // byte offset into h

            // ---- basis values for k = 8g..8g+7 : sin((k+1)*xa) ----
            float bas[8];
            bas[0] = __sinf((float)(8 * g + 1) * xa);
            bas[1] = __sinf((float)(8 * g + 2) * xa);
            float twoc = 2.0f * __cosf(xa);
            #pragma unroll
            for (int j = 2; j < 8; ++j)
                bas[j] = fmaf(twoc, bas[j-1], -bas[j-2]);

            short8 A;
            #pragma unroll
            for (int j = 0; j < 8; ++j)
                A[j] = (short)f2bf(bas[j] * scale);

            // ---- broadcast per-edge row data to all lanes (rows 4g+reg) ----
            float env_r[4], ux_r[4], uy_r[4], uz_r[4];
            int   hof_r[4];
            #pragma unroll
            for (int reg = 0; reg < 4; ++reg) {
                int src = 4 * g + reg;
                env_r[reg] = __shfl(env, src, 64);
                ux_r[reg]  = __shfl(ux,  src, 64);
                uy_r[reg]  = __shfl(uy,  src, 64);
                uz_r[reg]  = __shfl(uz,  src, 64);
                hof_r[reg] = __shfl(hof, src, 64);
            }
            const float* hp[4];
            #pragma unroll
            for (int reg = 0; reg < 4; ++reg)
                hp[reg] = (const float*)(hb + (size_t)(unsigned)hof_r[reg]) + c;

            // ---- 12 MFMA tiles + fused epilogue ----
            #pragma unroll
            for (int t = 0; t < 4; ++t) {       // delta_s channels 0..63
                f32x4 C = __builtin_amdgcn_mfma_f32_16x16x32_bf16(
                    A, Bf[t], (f32x4){0.f,0.f,0.f,0.f}, 0, 0, 0);
                #pragma unroll
                for (int reg = 0; reg < 4; ++reg) {
                    float hv = hp[reg][16 * t];
                    float filt = fmaf(bft[t], env_r[reg], C[reg]);
                    dsa[t] = fmaf(filt, hv, dsa[t]);
                }
            }
            #pragma unroll
            for (int t = 4; t < 8; ++t) {       // "b" channels 64..127 -> dv
                f32x4 C = __builtin_amdgcn_mfma_f32_16x16x32_bf16(
                    A, Bf[t], (f32x4){0.f,0.f,0.f,0.f}, 0, 0, 0);
                #pragma unroll
                for (int reg = 0; reg < 4; ++reg) {
                    float hv = hp[reg][16 * t];
                    float filt = fmaf(bft[t], env_r[reg], C[reg]);
                    float bh = filt * hv;
                    dvx[t-4] = fmaf(bh, ux_r[reg], dvx[t-4]);
                    dvy[t-4] = fmaf(bh, uy_r[reg], dvy[t-4]);
                    dvz[t-4] = fmaf(bh, uz_r[reg], dvz[t-4]);
                }
            }
            #pragma unroll
            for (int t = 8; t < 12; ++t) {      // "c" channels 128..191 -> csum
                f32x4 C = __builtin_amdgcn_mfma_f32_16x16x32_bf16(
                    A, Bf[t], (f32x4){0.f,0.f,0.f,0.f}, 0, 0, 0);
                #pragma unroll
                for (int reg = 0; reg < 4; ++reg) {
                    float hv = hp[reg][16 * t];
                    float filt = fmaf(bft[t], env_r[reg], C[reg]);
                    csm[t-8] = fmaf(filt, hv, csm[t-8]);
                }
            }
        }

        // ---- cross-lane reduce over the 4 row-groups (xor 16, 32) ----
        #pragma unroll
        for (int t = 0; t < 4; ++t) {
            dsa[t] += __shfl_xor(dsa[t], 16, 64); dsa[t] += __shfl_xor(dsa[t], 32, 64);
            csm[t] += __shfl_xor(csm[t], 16, 64); csm[t] += __shfl_xor(csm[t], 32, 64);
            dvx[t] += __shfl_xor(dvx[t], 16, 64); dvx[t] += __shfl_xor(dvx[t], 32, 64);
            dvy[t] += __shfl_xor(dvy[t], 16, 64); dvy[t] += __shfl_xor(dvy[t], 32, 64);
            dvz[t] += __shfl_xor(dvz[t], 16, 64); dvz[t] += __shfl_xor(dvz[t], 32, 64);
        }

        // lane (g,c) writes channel ch = 16g + c
        float dssel = (g==0) ? dsa[0] : (g==1) ? dsa[1] : (g==2) ? dsa[2] : dsa[3];
        float cssel = (g==0) ? csm[0] : (g==1) ? csm[1] : (g==2) ? csm[2] : csm[3];
        float vxsel = (g==0) ? dvx[0] : (g==1) ? dvx[1] : (g==2) ? dvx[2] : dvx[3];
        float vysel = (g==0) ? dvy[0] : (g==1) ? dvy[1] : (g==2) ? dvy[2] : dvy[3];
        float vzsel = (g==0) ? dvz[0] : (g==1) ? dvz[1] : (g==2) ? dvz[2] : dvz[3];

        int ch = 16 * g + c;
        size_t vb = (size_t)atom * TD + (size_t)ch * 3;
        float v0 = ve[vb + 0], v1 = ve[vb + 1], v2 = ve[vb + 2];
        dv[vb + 0] = fmaf(cssel, v0, vxsel);
        dv[vb + 1] = fmaf(cssel, v1, vysel);
        dv[vb + 2] = fmaf(cssel, v2, vzsel);
        ds[(size_t)atom * DCH + ch] = dssel;
    }
}

extern "C" void kernel_launch(void* const* d_in, const int* in_sizes, int n_in,
                              void* d_out, int out_size, void* d_ws, size_t ws_size,
                              hipStream_t stream) {
    const float* ve      = (const float*)d_in[0];
    const float* se      = (const float*)d_in[1];
    const float* nv      = (const float*)d_in[2];
    const int*   central = (const int*)  d_in[3];
    const int*   neigh   = (const int*)  d_in[4];
    const float* Wf      = (const float*)d_in[6];
    const float* bfil    = (const float*)d_in[7];
    const float* W1      = (const float*)d_in[8];
    const float* b1      = (const float*)d_in[9];
    const float* W2      = (const float*)d_in[10];
    const float* b2      = (const float*)d_in[11];

    const int N = in_sizes[1] / DCH;
    const int E = in_sizes[3];

    float* out = (float*)d_out;
    float* dv  = out;
    float* ds  = out + (size_t)N * TD;

    char* wsb = (char*)d_ws;
    size_t off = 0;
    auto wsalloc = [&](size_t bytes) -> void* {
        void* p = wsb + off;
        off = (off + bytes + 255) & ~(size_t)255;
        return p;
    };
    float*  h       = (float*) wsalloc((size_t)N * TD * 4);
    int*    counts  = (int*)   wsalloc((size_t)N * 4);
    int*    starts  = (int*)   wsalloc((size_t)N * 4);
    int*    pos     = (int*)   wsalloc((size_t)E * 4);
    float4* payload = (float4*)wsalloc((size_t)E * 16);
    int*    bsums   = (int*)   wsalloc(4096);

    const int nb1 = (N + 255) / 256;

    mlp_kernel<<<2048, 256, 0, stream>>>(se, W1, b1, W2, b2, h, N);

    hipMemsetAsync(counts, 0, (size_t)N * 4, stream);
    hist_kernel<<<2048, 256, 0, stream>>>(neigh, counts, pos, E);
    scan1_kernel<<<nb1, 256, 0, stream>>>(counts, starts, bsums, N);
    scan2_kernel<<<1, 512, 0, stream>>>(bsums, nb1);
    scan3_kernel<<<nb1, 256, 0, stream>>>(starts, bsums, N);
    fill_kernel<<<2048, 256, 0, stream>>>(nv, central, neigh, starts, pos, payload, E);
    gather_kernel<<<2048, 256, 0, stream>>>(payload, starts, counts, h, ve,
                                            Wf, bfil, dv, ds, N);
}

// Round 5
// 390.930 us; speedup vs baseline: 9.9493x; 1.8164x over previous
//
#include <hip/hip_runtime.h>
#include <math.h>

#define DCH 64
#define TD 192      // 3*D
#define RR 20
#define FCUT 5.0f

typedef __attribute__((ext_vector_type(8))) short short8;   // 8 bf16
typedef __attribute__((ext_vector_type(4))) float f32x4;

__device__ __forceinline__ unsigned short f2bf(float f) {   // f32 -> bf16 RNE
    unsigned int u = __float_as_uint(f);
    u += 0x7FFFu + ((u >> 16) & 1u);
    return (unsigned short)(u >> 16);
}

// ---------------- Kernel A: MFMA MLP, 16 atoms/wave, 64/block ---------------
// layer1: C1[16a x 64h] = se[16a x K64] @ W1[K64 x 64]; SiLU; LDS transpose;
// layer2: h[16a x 192] = hid[16a x K64] @ W2[K64 x 192].
__global__ __launch_bounds__(256, 2) void mlp_mfma_kernel(
    const float* __restrict__ se,
    const float* __restrict__ W1, const float* __restrict__ b1,
    const float* __restrict__ W2, const float* __restrict__ b2,
    float* __restrict__ h, int N)
{
    const int wid  = threadIdx.x >> 6;
    const int lane = threadIdx.x & 63;
    const int g    = lane >> 4;     // k-group / row-group
    const int c    = lane & 15;     // row (A) / col (B,C)

    __shared__ float hmid[4][16][68];   // per-wave [16 atoms][64+4 pad]

    // hoisted bf16 B fragments: lane(g,c) holds col c, k = kh*32 + 8g + j
    short8 W1f[4][2];
    float  b1t[4];
    #pragma unroll
    for (int t = 0; t < 4; ++t) {
        #pragma unroll
        for (int kh = 0; kh < 2; ++kh)
            #pragma unroll
            for (int j = 0; j < 8; ++j) {
                int k = kh * 32 + 8 * g + j;
                W1f[t][kh][j] = (short)f2bf(W1[k * DCH + 16 * t + c]);
            }
        b1t[t] = b1[16 * t + c];
    }
    short8 W2f[12][2];
    float  b2t[12];
    #pragma unroll
    for (int t = 0; t < 12; ++t) {
        #pragma unroll
        for (int kh = 0; kh < 2; ++kh)
            #pragma unroll
            for (int j = 0; j < 8; ++j) {
                int k = kh * 32 + 8 * g + j;
                W2f[t][kh][j] = (short)f2bf(W2[k * TD + 16 * t + c]);
            }
        b2t[t] = b2[16 * t + c];
    }

    for (int base = blockIdx.x * 64; base < N; base += gridDim.x * 64) {
        const int arow = base + wid * 16;       // this wave's atom block
        const int atom = arow + c;              // A-row owned by this lane
        const bool va  = atom < N;

        // ---- A fragments from se (f32 -> bf16) ----
        const float* sp = se + (size_t)(va ? atom : 0) * DCH;
        short8 A0, A1;
        #pragma unroll
        for (int kh = 0; kh < 2; ++kh) {
            float4 q0 = va ? *(const float4*)(sp + kh*32 + 8*g)     : make_float4(0,0,0,0);
            float4 q1 = va ? *(const float4*)(sp + kh*32 + 8*g + 4) : make_float4(0,0,0,0);
            short8& A = kh ? A1 : A0;
            A[0] = (short)f2bf(q0.x); A[1] = (short)f2bf(q0.y);
            A[2] = (short)f2bf(q0.z); A[3] = (short)f2bf(q0.w);
            A[4] = (short)f2bf(q1.x); A[5] = (short)f2bf(q1.y);
            A[6] = (short)f2bf(q1.z); A[7] = (short)f2bf(q1.w);
        }

        // ---- layer 1 + SiLU -> LDS ----
        #pragma unroll
        for (int t = 0; t < 4; ++t) {
            f32x4 C = {0.f, 0.f, 0.f, 0.f};
            C = __builtin_amdgcn_mfma_f32_16x16x32_bf16(A0, W1f[t][0], C, 0, 0, 0);
            C = __builtin_amdgcn_mfma_f32_16x16x32_bf16(A1, W1f[t][1], C, 0, 0, 0);
            #pragma unroll
            for (int reg = 0; reg < 4; ++reg) {
                float x = C[reg] + b1t[t];
                float s = x / (1.0f + __expf(-x));
                hmid[wid][4 * g + reg][16 * t + c] = s;
            }
        }
        __syncthreads();

        // ---- A fragments for layer 2 from LDS (row c, k-slice 8g..) ----
        short8 B0, B1;
        #pragma unroll
        for (int kh = 0; kh < 2; ++kh) {
            const float* hp = &hmid[wid][c][kh * 32 + 8 * g];
            float4 q0 = *(const float4*)(hp);
            float4 q1 = *(const float4*)(hp + 4);
            short8& A = kh ? B1 : B0;
            A[0] = (short)f2bf(q0.x); A[1] = (short)f2bf(q0.y);
            A[2] = (short)f2bf(q0.z); A[3] = (short)f2bf(q0.w);
            A[4] = (short)f2bf(q1.x); A[5] = (short)f2bf(q1.y);
            A[6] = (short)f2bf(q1.z); A[7] = (short)f2bf(q1.w);
        }

        // ---- layer 2 -> h ----
        #pragma unroll
        for (int t = 0; t < 12; ++t) {
            f32x4 C = {0.f, 0.f, 0.f, 0.f};
            C = __builtin_amdgcn_mfma_f32_16x16x32_bf16(B0, W2f[t][0], C, 0, 0, 0);
            C = __builtin_amdgcn_mfma_f32_16x16x32_bf16(B1, W2f[t][1], C, 0, 0, 0);
            #pragma unroll
            for (int reg = 0; reg < 4; ++reg) {
                int a2 = arow + 4 * g + reg;
                if (a2 < N)
                    h[(size_t)a2 * TD + 16 * t + c] = C[reg] + b2t[t];
            }
        }
        __syncthreads();
    }
}

// ---------------- CSR build: histogram, scan, fill --------------------------
__global__ void hist_kernel(const int* __restrict__ neigh,
                            int* __restrict__ counts, int* __restrict__ pos, int E)
{
    int stride = gridDim.x * blockDim.x;
    for (int e = blockIdx.x * blockDim.x + threadIdx.x; e < E; e += stride)
        pos[e] = atomicAdd(&counts[neigh[e]], 1);
}

__global__ __launch_bounds__(256) void scan1_kernel(
    const int* __restrict__ counts, int* __restrict__ starts,
    int* __restrict__ bsums, int N)
{
    int tid = threadIdx.x;
    int gid = blockIdx.x * 256 + tid;
    int v = (gid < N) ? counts[gid] : 0;
    int lane = tid & 63, wid = tid >> 6;
    int x = v;
    #pragma unroll
    for (int off = 1; off < 64; off <<= 1) {
        int y = __shfl_up(x, off, 64);
        if (lane >= off) x += y;
    }
    __shared__ int wsum[4];
    if (lane == 63) wsum[wid] = x;
    __syncthreads();
    int add = 0;
    for (int w = 0; w < wid; ++w) add += wsum[w];
    int incl = x + add;
    if (gid < N) starts[gid] = incl - v;          // block-local exclusive
    if (tid == 255) bsums[blockIdx.x] = incl;     // block total
}

__global__ __launch_bounds__(512) void scan2_kernel(int* __restrict__ bsums, int M)
{
    int tid = threadIdx.x;
    int v = (tid < M) ? bsums[tid] : 0;
    int lane = tid & 63, wid = tid >> 6;
    int x = v;
    #pragma unroll
    for (int off = 1; off < 64; off <<= 1) {
        int y = __shfl_up(x, off, 64);
        if (lane >= off) x += y;
    }
    __shared__ int wsum[8];
    if (lane == 63) wsum[wid] = x;
    __syncthreads();
    int add = 0;
    for (int w = 0; w < wid; ++w) add += wsum[w];
    int incl = x + add;
    if (tid < M) bsums[tid] = incl - v;           // exclusive scan in place
}

__global__ __launch_bounds__(256) void scan3_kernel(
    int* __restrict__ starts, const int* __restrict__ bsums, int N)
{
    int gid = blockIdx.x * 256 + threadIdx.x;
    if (gid < N) starts[gid] += bsums[blockIdx.x];
}

__global__ void fill_kernel(const float* __restrict__ nv, const int* __restrict__ central,
                            const int* __restrict__ neigh, const int* __restrict__ starts,
                            const int* __restrict__ pos, float4* __restrict__ payload, int E)
{
    int stride = gridDim.x * blockDim.x;
    for (int e = blockIdx.x * blockDim.x + threadIdx.x; e < E; e += stride) {
        int slot = starts[neigh[e]] + pos[e];
        payload[slot] = make_float4(nv[(size_t)e*3+0], nv[(size_t)e*3+1],
                                    nv[(size_t)e*3+2], __int_as_float(central[e]));
    }
}

// ---------------- Kernel C: per-atom gather, MFMA filter --------------------
__global__ __launch_bounds__(256) void gather_kernel(
    const float4* __restrict__ payload, const int* __restrict__ starts,
    const int* __restrict__ counts, const float* __restrict__ h,
    const float* __restrict__ ve, const float* __restrict__ Wf,
    const float* __restrict__ bfil,
    float* __restrict__ dv, float* __restrict__ ds, int N)
{
    const int wid  = threadIdx.x >> 6;
    const int lane = threadIdx.x & 63;
    const int g    = lane >> 4;     // k-group (A/B), row-group (C)
    const int c    = lane & 15;     // own edge row (A), channel-in-tile (B/C)

    short8 Bf[12];
    float  bft[12];
    #pragma unroll
    for (int t = 0; t < 12; ++t) {
        #pragma unroll
        for (int j = 0; j < 8; ++j) {
            int r = 8 * g + j;
            float w = (r < RR) ? Wf[r * TD + 16 * t + c] : 0.0f;
            Bf[t][j] = (short)f2bf(w);
        }
        bft[t] = bfil[16 * t + c];
    }

    const float BC = sqrtf(2.0f / FCUT);
    const float XK = (float)(M_PI / (double)FCUT);
    const char* hb = (const char*)h;

    for (int atom = blockIdx.x * 4 + wid; atom < N; atom += gridDim.x * 4) {
        const int s   = starts[atom];
        const int cnt = counts[atom];

        float dsa[4] = {0,0,0,0};
        float csm[4] = {0,0,0,0};
        float dvx[4] = {0,0,0,0};
        float dvy[4] = {0,0,0,0};
        float dvz[4] = {0,0,0,0};

        for (int i0 = 0; i0 < cnt; i0 += 16) {
            const bool valid = (i0 + c) < cnt;
            float4 p = valid ? payload[s + i0 + c]
                             : make_float4(1.0f, 0.0f, 0.0f, __int_as_float(0));
            float dist = sqrtf(p.x*p.x + p.y*p.y + p.z*p.z);
            float inv  = 1.0f / dist;
            float xa   = dist * XK;

            float u  = dist * (1.0f / FCUT);
            float u2 = u * u;
            float u6 = u2 * u2 * u2;
            float env = 1.0f + u6 * (-28.0f + u * (48.0f - 21.0f * u));
            env = (dist < FCUT && valid) ? env : 0.0f;
            float scale = BC * inv * env;

            float ux = p.x * inv, uy = p.y * inv, uz = p.z * inv;
            int   hof = __float_as_int(p.w) * (TD * 4);   // byte offset into h

            float bas[8];
            bas[0] = __sinf((float)(8 * g + 1) * xa);
            bas[1] = __sinf((float)(8 * g + 2) * xa);
            float twoc = 2.0f * __cosf(xa);
            #pragma unroll
            for (int j = 2; j < 8; ++j)
                bas[j] = fmaf(twoc, bas[j-1], -bas[j-2]);

            short8 A;
            #pragma unroll
            for (int j = 0; j < 8; ++j)
                A[j] = (short)f2bf(bas[j] * scale);

            float env_r[4], ux_r[4], uy_r[4], uz_r[4];
            int   hof_r[4];
            #pragma unroll
            for (int reg = 0; reg < 4; ++reg) {
                int src = 4 * g + reg;
                env_r[reg] = __shfl(env, src, 64);
                ux_r[reg]  = __shfl(ux,  src, 64);
                uy_r[reg]  = __shfl(uy,  src, 64);
                uz_r[reg]  = __shfl(uz,  src, 64);
                hof_r[reg] = __shfl(hof, src, 64);
            }
            const float* hp[4];
            #pragma unroll
            for (int reg = 0; reg < 4; ++reg)
                hp[reg] = (const float*)(hb + (size_t)(unsigned)hof_r[reg]) + c;

            #pragma unroll
            for (int t = 0; t < 4; ++t) {       // delta_s channels 0..63
                f32x4 C = __builtin_amdgcn_mfma_f32_16x16x32_bf16(
                    A, Bf[t], (f32x4){0.f,0.f,0.f,0.f}, 0, 0, 0);
                #pragma unroll
                for (int reg = 0; reg < 4; ++reg) {
                    float hv = hp[reg][16 * t];
                    float filt = fmaf(bft[t], env_r[reg], C[reg]);
                    dsa[t] = fmaf(filt, hv, dsa[t]);
                }
            }
            #pragma unroll
            for (int t = 4; t < 8; ++t) {       // "b" channels 64..127 -> dv
                f32x4 C = __builtin_amdgcn_mfma_f32_16x16x32_bf16(
                    A, Bf[t], (f32x4){0.f,0.f,0.f,0.f}, 0, 0, 0);
                #pragma unroll
                for (int reg = 0; reg < 4; ++reg) {
                    float hv = hp[reg][16 * t];
                    float filt = fmaf(bft[t], env_r[reg], C[reg]);
                    float bh = filt * hv;
                    dvx[t-4] = fmaf(bh, ux_r[reg], dvx[t-4]);
                    dvy[t-4] = fmaf(bh, uy_r[reg], dvy[t-4]);
                    dvz[t-4] = fmaf(bh, uz_r[reg], dvz[t-4]);
                }
            }
            #pragma unroll
            for (int t = 8; t < 12; ++t) {      // "c" channels 128..191 -> csum
                f32x4 C = __builtin_amdgcn_mfma_f32_16x16x32_bf16(
                    A, Bf[t], (f32x4){0.f,0.f,0.f,0.f}, 0, 0, 0);
                #pragma unroll
                for (int reg = 0; reg < 4; ++reg) {
                    float hv = hp[reg][16 * t];
                    float filt = fmaf(bft[t], env_r[reg], C[reg]);
                    csm[t-8] = fmaf(filt, hv, csm[t-8]);
                }
            }
        }

        #pragma unroll
        for (int t = 0; t < 4; ++t) {
            dsa[t] += __shfl_xor(dsa[t], 16, 64); dsa[t] += __shfl_xor(dsa[t], 32, 64);
            csm[t] += __shfl_xor(csm[t], 16, 64); csm[t] += __shfl_xor(csm[t], 32, 64);
            dvx[t] += __shfl_xor(dvx[t], 16, 64); dvx[t] += __shfl_xor(dvx[t], 32, 64);
            dvy[t] += __shfl_xor(dvy[t], 16, 64); dvy[t] += __shfl_xor(dvy[t], 32, 64);
            dvz[t] += __shfl_xor(dvz[t], 16, 64); dvz[t] += __shfl_xor(dvz[t], 32, 64);
        }

        float dssel = (g==0) ? dsa[0] : (g==1) ? dsa[1] : (g==2) ? dsa[2] : dsa[3];
        float cssel = (g==0) ? csm[0] : (g==1) ? csm[1] : (g==2) ? csm[2] : csm[3];
        float vxsel = (g==0) ? dvx[0] : (g==1) ? dvx[1] : (g==2) ? dvx[2] : dvx[3];
        float vysel = (g==0) ? dvy[0] : (g==1) ? dvy[1] : (g==2) ? dvy[2] : dvy[3];
        float vzsel = (g==0) ? dvz[0] : (g==1) ? dvz[1] : (g==2) ? dvz[2] : dvz[3];

        int ch = 16 * g + c;
        size_t vb = (size_t)atom * TD + (size_t)ch * 3;
        float v0 = ve[vb + 0], v1 = ve[vb + 1], v2 = ve[vb + 2];
        dv[vb + 0] = fmaf(cssel, v0, vxsel);
        dv[vb + 1] = fmaf(cssel, v1, vysel);
        dv[vb + 2] = fmaf(cssel, v2, vzsel);
        ds[(size_t)atom * DCH + ch] = dssel;
    }
}

extern "C" void kernel_launch(void* const* d_in, const int* in_sizes, int n_in,
                              void* d_out, int out_size, void* d_ws, size_t ws_size,
                              hipStream_t stream) {
    const float* ve      = (const float*)d_in[0];
    const float* se      = (const float*)d_in[1];
    const float* nv      = (const float*)d_in[2];
    const int*   central = (const int*)  d_in[3];
    const int*   neigh   = (const int*)  d_in[4];
    const float* Wf      = (const float*)d_in[6];
    const float* bfil    = (const float*)d_in[7];
    const float* W1      = (const float*)d_in[8];
    const float* b1      = (const float*)d_in[9];
    const float* W2      = (const float*)d_in[10];
    const float* b2      = (const float*)d_in[11];

    const int N = in_sizes[1] / DCH;
    const int E = in_sizes[3];

    float* out = (float*)d_out;
    float* dv  = out;
    float* ds  = out + (size_t)N * TD;

    char* wsb = (char*)d_ws;
    size_t off = 0;
    auto wsalloc = [&](size_t bytes) -> void* {
        void* p = wsb + off;
        off = (off + bytes + 255) & ~(size_t)255;
        return p;
    };
    float*  h       = (float*) wsalloc((size_t)N * TD * 4);
    int*    counts  = (int*)   wsalloc((size_t)N * 4);
    int*    starts  = (int*)   wsalloc((size_t)N * 4);
    int*    pos     = (int*)   wsalloc((size_t)E * 4);
    float4* payload = (float4*)wsalloc((size_t)E * 16);
    int*    bsums   = (int*)   wsalloc(4096);

    const int nb1 = (N + 255) / 256;
    const int nbm = (N + 63) / 64;

    mlp_mfma_kernel<<<nbm, 256, 0, stream>>>(se, W1, b1, W2, b2, h, N);

    hipMemsetAsync(counts, 0, (size_t)N * 4, stream);
    hist_kernel<<<2048, 256, 0, stream>>>(neigh, counts, pos, E);
    scan1_kernel<<<nb1, 256, 0, stream>>>(counts, starts, bsums, N);
    scan2_kernel<<<1, 512, 0, stream>>>(bsums, nb1);
    scan3_kernel<<<nb1, 256, 0, stream>>>(starts, bsums, N);
    fill_kernel<<<2048, 256, 0, stream>>>(nv, central, neigh, starts, pos, payload, E);
    gather_kernel<<<2048, 256, 0, stream>>>(payload, starts, counts, h, ve,
                                            Wf, bfil, dv, ds, N);
}

// Round 6
// 353.965 us; speedup vs baseline: 10.9883x; 1.1044x over previous
//
#include <hip/hip_runtime.h>
#include <math.h>

#define DCH 64
#define TD 192      // 3*D
#define RR 20
#define FCUT 5.0f

typedef __attribute__((ext_vector_type(8))) short short8;   // 8 bf16
typedef __attribute__((ext_vector_type(4))) float f32x4;
typedef __attribute__((ext_vector_type(2))) unsigned int u32x2;

__device__ __forceinline__ unsigned short f2bf(float f) {   // f32 -> bf16 RNE
    unsigned int u = __float_as_uint(f);
    u += 0x7FFFu + ((u >> 16) & 1u);
    return (unsigned short)(u >> 16);
}
__device__ __forceinline__ float bflo(unsigned int u) {     // low bf16 -> f32
    return __uint_as_float(u << 16);
}
__device__ __forceinline__ float bfhi(unsigned int u) {     // high bf16 -> f32
    return __uint_as_float(u & 0xFFFF0000u);
}

// ---------------- Kernel A: MFMA MLP, 16 atoms/wave, 64/block ---------------
// h stored bf16 as h2[atom][c(16)][t(12)]  (384 B/atom) for the gather's
// 3x dwordx2 per-row read pattern.
__global__ __launch_bounds__(256, 2) void mlp_mfma_kernel(
    const float* __restrict__ se,
    const float* __restrict__ W1, const float* __restrict__ b1,
    const float* __restrict__ W2, const float* __restrict__ b2,
    unsigned short* __restrict__ h2, int N)
{
    const int wid  = threadIdx.x >> 6;
    const int lane = threadIdx.x & 63;
    const int g    = lane >> 4;     // k-group / row-group
    const int c    = lane & 15;     // row (A) / col (B,C)

    __shared__ float hmid[4][16][68];            // per-wave hidden [16a][64+4]
    __shared__ unsigned short hstage[4][16][196]; // per-wave h out (stride 196)

    short8 W1f[4][2];
    float  b1t[4];
    #pragma unroll
    for (int t = 0; t < 4; ++t) {
        #pragma unroll
        for (int kh = 0; kh < 2; ++kh)
            #pragma unroll
            for (int j = 0; j < 8; ++j) {
                int k = kh * 32 + 8 * g + j;
                W1f[t][kh][j] = (short)f2bf(W1[k * DCH + 16 * t + c]);
            }
        b1t[t] = b1[16 * t + c];
    }
    short8 W2f[12][2];
    float  b2t[12];
    #pragma unroll
    for (int t = 0; t < 12; ++t) {
        #pragma unroll
        for (int kh = 0; kh < 2; ++kh)
            #pragma unroll
            for (int j = 0; j < 8; ++j) {
                int k = kh * 32 + 8 * g + j;
                W2f[t][kh][j] = (short)f2bf(W2[k * TD + 16 * t + c]);
            }
        b2t[t] = b2[16 * t + c];
    }

    for (int base = blockIdx.x * 64; base < N; base += gridDim.x * 64) {
        const int arow = base + wid * 16;
        const int atom = arow + c;
        const bool va  = atom < N;

        // ---- A fragments from se (f32 -> bf16), NT streaming loads ----
        const float* sp = se + (size_t)(va ? atom : 0) * DCH;
        short8 A0, A1;
        #pragma unroll
        for (int kh = 0; kh < 2; ++kh) {
            f32x4 q0 = va ? __builtin_nontemporal_load((const f32x4*)(sp + kh*32 + 8*g))
                          : (f32x4){0.f,0.f,0.f,0.f};
            f32x4 q1 = va ? __builtin_nontemporal_load((const f32x4*)(sp + kh*32 + 8*g + 4))
                          : (f32x4){0.f,0.f,0.f,0.f};
            short8& A = kh ? A1 : A0;
            A[0] = (short)f2bf(q0[0]); A[1] = (short)f2bf(q0[1]);
            A[2] = (short)f2bf(q0[2]); A[3] = (short)f2bf(q0[3]);
            A[4] = (short)f2bf(q1[0]); A[5] = (short)f2bf(q1[1]);
            A[6] = (short)f2bf(q1[2]); A[7] = (short)f2bf(q1[3]);
        }

        // ---- layer 1 + SiLU -> LDS ----
        #pragma unroll
        for (int t = 0; t < 4; ++t) {
            f32x4 C = {0.f, 0.f, 0.f, 0.f};
            C = __builtin_amdgcn_mfma_f32_16x16x32_bf16(A0, W1f[t][0], C, 0, 0, 0);
            C = __builtin_amdgcn_mfma_f32_16x16x32_bf16(A1, W1f[t][1], C, 0, 0, 0);
            #pragma unroll
            for (int reg = 0; reg < 4; ++reg) {
                float x = C[reg] + b1t[t];
                float s = x / (1.0f + __expf(-x));
                hmid[wid][4 * g + reg][16 * t + c] = s;
            }
        }
        __syncthreads();

        // ---- layer-2 A fragments from LDS (row c, k-slice 8g..) ----
        short8 B0, B1;
        #pragma unroll
        for (int kh = 0; kh < 2; ++kh) {
            const float* hp = &hmid[wid][c][kh * 32 + 8 * g];
            f32x4 q0 = *(const f32x4*)(hp);
            f32x4 q1 = *(const f32x4*)(hp + 4);
            short8& A = kh ? B1 : B0;
            A[0] = (short)f2bf(q0[0]); A[1] = (short)f2bf(q0[1]);
            A[2] = (short)f2bf(q0[2]); A[3] = (short)f2bf(q0[3]);
            A[4] = (short)f2bf(q1[0]); A[5] = (short)f2bf(q1[1]);
            A[6] = (short)f2bf(q1[2]); A[7] = (short)f2bf(q1[3]);
        }

        // ---- layer 2 -> hstage (bf16, transposed per-atom layout) ----
        #pragma unroll
        for (int t = 0; t < 12; ++t) {
            f32x4 C = {0.f, 0.f, 0.f, 0.f};
            C = __builtin_amdgcn_mfma_f32_16x16x32_bf16(B0, W2f[t][0], C, 0, 0, 0);
            C = __builtin_amdgcn_mfma_f32_16x16x32_bf16(B1, W2f[t][1], C, 0, 0, 0);
            #pragma unroll
            for (int reg = 0; reg < 4; ++reg)
                hstage[wid][4 * g + reg][c * 12 + t] = f2bf(C[reg] + b2t[t]);
        }
        __syncthreads();   // orders hstage cross-lane AND hmid reuse

        // ---- coalesced copy-out: 384 B/atom, 48 lanes x 8 B ----
        if (lane < 48) {
            #pragma unroll
            for (int i = 0; i < 16; ++i) {
                int a2 = arow + i;
                if (a2 < N)
                    *(u32x2*)((char*)h2 + (size_t)a2 * 384 + lane * 8) =
                        *(const u32x2*)(&hstage[wid][i][lane * 4]);
            }
        }
    }
}

// ---------------- CSR build: histogram, scan, fill --------------------------
__global__ void hist_kernel(const int* __restrict__ neigh,
                            int* __restrict__ counts, int* __restrict__ pos, int E)
{
    int stride = gridDim.x * blockDim.x;
    for (int e = blockIdx.x * blockDim.x + threadIdx.x; e < E; e += stride) {
        int p = atomicAdd(&counts[neigh[e]], 1);
        __builtin_nontemporal_store(p, &pos[e]);
    }
}

__global__ __launch_bounds__(256) void scan1_kernel(
    const int* __restrict__ counts, int* __restrict__ starts,
    int* __restrict__ bsums, int N)
{
    int tid = threadIdx.x;
    int gid = blockIdx.x * 256 + tid;
    int v = (gid < N) ? counts[gid] : 0;
    int lane = tid & 63, wid = tid >> 6;
    int x = v;
    #pragma unroll
    for (int off = 1; off < 64; off <<= 1) {
        int y = __shfl_up(x, off, 64);
        if (lane >= off) x += y;
    }
    __shared__ int wsum[4];
    if (lane == 63) wsum[wid] = x;
    __syncthreads();
    int add = 0;
    for (int w = 0; w < wid; ++w) add += wsum[w];
    int incl = x + add;
    if (gid < N) starts[gid] = incl - v;
    if (tid == 255) bsums[blockIdx.x] = incl;
}

__global__ __launch_bounds__(512) void scan2_kernel(int* __restrict__ bsums, int M)
{
    int tid = threadIdx.x;
    int v = (tid < M) ? bsums[tid] : 0;
    int lane = tid & 63, wid = tid >> 6;
    int x = v;
    #pragma unroll
    for (int off = 1; off < 64; off <<= 1) {
        int y = __shfl_up(x, off, 64);
        if (lane >= off) x += y;
    }
    __shared__ int wsum[8];
    if (lane == 63) wsum[wid] = x;
    __syncthreads();
    int add = 0;
    for (int w = 0; w < wid; ++w) add += wsum[w];
    int incl = x + add;
    if (tid < M) bsums[tid] = incl - v;
}

__global__ __launch_bounds__(256) void scan3_kernel(
    int* __restrict__ starts, const int* __restrict__ bsums, int N)
{
    int gid = blockIdx.x * 256 + threadIdx.x;
    if (gid < N) starts[gid] += bsums[blockIdx.x];
}

__global__ void fill_kernel(const float* __restrict__ nv, const int* __restrict__ central,
                            const int* __restrict__ neigh, const int* __restrict__ starts,
                            const int* __restrict__ pos, f32x4* __restrict__ payload, int E)
{
    int stride = gridDim.x * blockDim.x;
    for (int e = blockIdx.x * blockDim.x + threadIdx.x; e < E; e += stride) {
        int slot = starts[neigh[e]] + pos[e];
        f32x4 pay;
        pay[0] = __builtin_nontemporal_load(&nv[(size_t)e*3+0]);
        pay[1] = __builtin_nontemporal_load(&nv[(size_t)e*3+1]);
        pay[2] = __builtin_nontemporal_load(&nv[(size_t)e*3+2]);
        pay[3] = __int_as_float(central[e]);
        __builtin_nontemporal_store(pay, &payload[slot]);
    }
}

// ---------------- Kernel C: per-atom gather, MFMA filter --------------------
__global__ __launch_bounds__(256) void gather_kernel(
    const f32x4* __restrict__ payload, const int* __restrict__ starts,
    const int* __restrict__ counts, const unsigned short* __restrict__ h2,
    const float* __restrict__ ve, const float* __restrict__ Wf,
    const float* __restrict__ bfil,
    float* __restrict__ dv, float* __restrict__ ds, int N)
{
    const int wid  = threadIdx.x >> 6;
    const int lane = threadIdx.x & 63;
    const int g    = lane >> 4;     // k-group (A/B), row-group (C)
    const int c    = lane & 15;     // own edge row (A), channel-in-tile (B/C)

    short8 Bf[12];
    float  bft[12];
    #pragma unroll
    for (int t = 0; t < 12; ++t) {
        #pragma unroll
        for (int j = 0; j < 8; ++j) {
            int r = 8 * g + j;
            float w = (r < RR) ? Wf[r * TD + 16 * t + c] : 0.0f;
            Bf[t][j] = (short)f2bf(w);
        }
        bft[t] = bfil[16 * t + c];
    }

    const float BC = sqrtf(2.0f / FCUT);
    const float XK = (float)(M_PI / (double)FCUT);
    const char* hb = (const char*)h2;

    for (int atom = blockIdx.x * 4 + wid; atom < N; atom += gridDim.x * 4) {
        const int s   = starts[atom];
        const int cnt = counts[atom];

        float dsa[4] = {0,0,0,0};
        float csm[4] = {0,0,0,0};
        float dvx[4] = {0,0,0,0};
        float dvy[4] = {0,0,0,0};
        float dvz[4] = {0,0,0,0};

        for (int i0 = 0; i0 < cnt; i0 += 16) {
            const bool valid = (i0 + c) < cnt;
            f32x4 p = valid ? __builtin_nontemporal_load(&payload[s + i0 + c])
                            : (f32x4){1.0f, 0.0f, 0.0f, 0.0f};
            float dist = sqrtf(p[0]*p[0] + p[1]*p[1] + p[2]*p[2]);
            float inv  = 1.0f / dist;
            float xa   = dist * XK;

            float u  = dist * (1.0f / FCUT);
            float u2 = u * u;
            float u6 = u2 * u2 * u2;
            float env = 1.0f + u6 * (-28.0f + u * (48.0f - 21.0f * u));
            env = (dist < FCUT && valid) ? env : 0.0f;
            float scale = BC * inv * env;

            float ux = p[0] * inv, uy = p[1] * inv, uz = p[2] * inv;
            int   ca  = valid ? __float_as_int(p[3]) : 0;
            int   hof = ca * 384;                       // byte offset into h2

            float bas[8];
            bas[0] = __sinf((float)(8 * g + 1) * xa);
            bas[1] = __sinf((float)(8 * g + 2) * xa);
            float twoc = 2.0f * __cosf(xa);
            #pragma unroll
            for (int j = 2; j < 8; ++j)
                bas[j] = fmaf(twoc, bas[j-1], -bas[j-2]);

            short8 A;
            #pragma unroll
            for (int j = 0; j < 8; ++j)
                A[j] = (short)f2bf(bas[j] * scale);

            float env_r[4], ux_r[4], uy_r[4], uz_r[4];
            int   hof_r[4];
            #pragma unroll
            for (int reg = 0; reg < 4; ++reg) {
                int src = 4 * g + reg;
                env_r[reg] = __shfl(env, src, 64);
                ux_r[reg]  = __shfl(ux,  src, 64);
                uy_r[reg]  = __shfl(uy,  src, 64);
                uz_r[reg]  = __shfl(uz,  src, 64);
                hof_r[reg] = __shfl(hof, src, 64);
            }

            // issue the 12 h row-loads early (cached; latency hides under MFMA)
            u32x2 hq[4][3];
            #pragma unroll
            for (int reg = 0; reg < 4; ++reg) {
                const char* rp = hb + (size_t)(unsigned)hof_r[reg] + c * 24;
                hq[reg][0] = *(const u32x2*)(rp);
                hq[reg][1] = *(const u32x2*)(rp + 8);
                hq[reg][2] = *(const u32x2*)(rp + 16);
            }

            #pragma unroll
            for (int t = 0; t < 12; ++t) {
                f32x4 C = __builtin_amdgcn_mfma_f32_16x16x32_bf16(
                    A, Bf[t], (f32x4){0.f,0.f,0.f,0.f}, 0, 0, 0);
                #pragma unroll
                for (int reg = 0; reg < 4; ++reg) {
                    unsigned int w = hq[reg][t >> 2][(t >> 1) & 1];
                    float hv = (t & 1) ? bfhi(w) : bflo(w);
                    float filt = fmaf(bft[t], env_r[reg], C[reg]);
                    if (t < 4) {
                        dsa[t] = fmaf(filt, hv, dsa[t]);
                    } else if (t < 8) {
                        float bh = filt * hv;
                        dvx[t-4] = fmaf(bh, ux_r[reg], dvx[t-4]);
                        dvy[t-4] = fmaf(bh, uy_r[reg], dvy[t-4]);
                        dvz[t-4] = fmaf(bh, uz_r[reg], dvz[t-4]);
                    } else {
                        csm[t-8] = fmaf(filt, hv, csm[t-8]);
                    }
                }
            }
        }

        #pragma unroll
        for (int t = 0; t < 4; ++t) {
            dsa[t] += __shfl_xor(dsa[t], 16, 64); dsa[t] += __shfl_xor(dsa[t], 32, 64);
            csm[t] += __shfl_xor(csm[t], 16, 64); csm[t] += __shfl_xor(csm[t], 32, 64);
            dvx[t] += __shfl_xor(dvx[t], 16, 64); dvx[t] += __shfl_xor(dvx[t], 32, 64);
            dvy[t] += __shfl_xor(dvy[t], 16, 64); dvy[t] += __shfl_xor(dvy[t], 32, 64);
            dvz[t] += __shfl_xor(dvz[t], 16, 64); dvz[t] += __shfl_xor(dvz[t], 32, 64);
        }

        float dssel = (g==0) ? dsa[0] : (g==1) ? dsa[1] : (g==2) ? dsa[2] : dsa[3];
        float cssel = (g==0) ? csm[0] : (g==1) ? csm[1] : (g==2) ? csm[2] : csm[3];
        float vxsel = (g==0) ? dvx[0] : (g==1) ? dvx[1] : (g==2) ? dvx[2] : dvx[3];
        float vysel = (g==0) ? dvy[0] : (g==1) ? dvy[1] : (g==2) ? dvy[2] : dvy[3];
        float vzsel = (g==0) ? dvz[0] : (g==1) ? dvz[1] : (g==2) ? dvz[2] : dvz[3];

        int ch = 16 * g + c;
        size_t vb = (size_t)atom * TD + (size_t)ch * 3;
        float v0 = __builtin_nontemporal_load(&ve[vb + 0]);
        float v1 = __builtin_nontemporal_load(&ve[vb + 1]);
        float v2 = __builtin_nontemporal_load(&ve[vb + 2]);
        __builtin_nontemporal_store(fmaf(cssel, v0, vxsel), &dv[vb + 0]);
        __builtin_nontemporal_store(fmaf(cssel, v1, vysel), &dv[vb + 1]);
        __builtin_nontemporal_store(fmaf(cssel, v2, vzsel), &dv[vb + 2]);
        __builtin_nontemporal_store(dssel, &ds[(size_t)atom * DCH + ch]);
    }
}

extern "C" void kernel_launch(void* const* d_in, const int* in_sizes, int n_in,
                              void* d_out, int out_size, void* d_ws, size_t ws_size,
                              hipStream_t stream) {
    const float* ve      = (const float*)d_in[0];
    const float* se      = (const float*)d_in[1];
    const float* nv      = (const float*)d_in[2];
    const int*   central = (const int*)  d_in[3];
    const int*   neigh   = (const int*)  d_in[4];
    const float* Wf      = (const float*)d_in[6];
    const float* bfil    = (const float*)d_in[7];
    const float* W1      = (const float*)d_in[8];
    const float* b1      = (const float*)d_in[9];
    const float* W2      = (const float*)d_in[10];
    const float* b2      = (const float*)d_in[11];

    const int N = in_sizes[1] / DCH;
    const int E = in_sizes[3];

    float* out = (float*)d_out;
    float* dv  = out;
    float* ds  = out + (size_t)N * TD;

    char* wsb = (char*)d_ws;
    size_t off = 0;
    auto wsalloc = [&](size_t bytes) -> void* {
        void* p = wsb + off;
        off = (off + bytes + 255) & ~(size_t)255;
        return p;
    };
    unsigned short* h2      = (unsigned short*)wsalloc((size_t)N * 192 * 2);
    int*            counts  = (int*)   wsalloc((size_t)N * 4);
    int*            starts  = (int*)   wsalloc((size_t)N * 4);
    int*            pos     = (int*)   wsalloc((size_t)E * 4);
    f32x4*          payload = (f32x4*) wsalloc((size_t)E * 16);
    int*            bsums   = (int*)   wsalloc(4096);

    const int nb1 = (N + 255) / 256;
    const int nbm = (N + 63) / 64;

    mlp_mfma_kernel<<<nbm, 256, 0, stream>>>(se, W1, b1, W2, b2, h2, N);

    hipMemsetAsync(counts, 0, (size_t)N * 4, stream);
    hist_kernel<<<2048, 256, 0, stream>>>(neigh, counts, pos, E);
    scan1_kernel<<<nb1, 256, 0, stream>>>(counts, starts, bsums, N);
    scan2_kernel<<<1, 512, 0, stream>>>(bsums, nb1);
    scan3_kernel<<<nb1, 256, 0, stream>>>(starts, bsums, N);
    fill_kernel<<<2048, 256, 0, stream>>>(nv, central, neigh, starts, pos, payload, E);
    gather_kernel<<<2048, 256, 0, stream>>>(payload, starts, counts, h2, ve,
                                            Wf, bfil, dv, ds, N);
}